// Round 4
// baseline (577.576 us; speedup 1.0000x reference)
//
#include <hip/hip_runtime.h>
#include <math.h>

// Problem constants
#define NTOT 16384        // N = B*T
#define GG 2
#define MM 1024
#define DD 256

// Output layout (flat float32)
#define OFF_Q  ((size_t)0)
#define OFF_CP ((size_t)8388608)
#define OFF_PP ((size_t)8388610)
#define OFF_I  ((size_t)8388612)
#define OFF_L  ((size_t)8421380)

#define SHIFT 40.0f       // row-constant logit shift (softmax/argmax invariant)
#define REFINE_GAP 0.03f  // fp64 re-check threshold (approx z err << this)

typedef __attribute__((ext_vector_type(8))) short bf16x8;
typedef __attribute__((ext_vector_type(4))) float f32x4;
typedef unsigned short u16;
typedef unsigned int u32;

__device__ inline float wave_sum_f(float v) {
#pragma unroll
  for (int o = 32; o > 0; o >>= 1) v += __shfl_xor(v, o);
  return v;
}
__device__ inline u16 f2bf(float f) {
  u32 u = __float_as_uint(f);
  return (u16)((u + 0x7fffu + ((u >> 16) & 1u)) >> 16);
}
__device__ inline float bf2f(u16 h) {
  return __uint_as_float(((u32)h) << 16);
}
// async 16B global->LDS (LDS dest = wave-uniform base + lane*16)
__device__ inline void async16(const void* g, void* l) {
  __builtin_amdgcn_global_load_lds(
      (const __attribute__((address_space(1))) u32*)g,
      (__attribute__((address_space(3))) u32*)l, 16, 0, 0);
}

// ============ ws layout ============
// 0       sq_e f32[2048]
// 8192    avg  f32[2048]
// 16384   hist i32[2048]
// 24576   loss double
// 32768   invZ f32[2*16384]          (128KB)
// 163840  eh_sw u16[2*1024*256]      (1MB, MFMA-frag swizzled, 32-col tiles)
// 1212416 el_sw u16[2*1024*256]      (1MB)
// 2260992 est  u16[2*1024*16384]     (67MB, [g][m][n] bf16)
#define WS_INVZ   32768
#define WS_EHSW   163840
#define WS_ELSW   1212416
#define WS_EST    2260992

// ---- init A: sq_e + zero hist/loss ----
__global__ void vq_init2(const float* __restrict__ emb, float* __restrict__ sq_e,
                         float* __restrict__ avg, int* __restrict__ hist,
                         double* __restrict__ loss) {
  const int row = blockIdx.x * 4 + (threadIdx.x >> 6);
  const int lane = threadIdx.x & 63;
  float4 e4 = *(const float4*)&emb[(size_t)row * DD + lane * 4];
  float s = e4.x * e4.x + e4.y * e4.y + e4.z * e4.z + e4.w * e4.w;
  s = wave_sum_f(s);
  if (lane == 0) sq_e[row] = s;
  if (blockIdx.x == 0) {
    for (int i = threadIdx.x; i < GG * MM; i += 256) { avg[i] = 0.f; hist[i] = 0; }
    if (threadIdx.x == 0) *loss = 0.0;
  }
}

// ---- init B: swizzled hi/lo tables in MFMA-frag chunk order, 32-col tiles.
// chunk(g,ct,ks,cg,quad,l15) = B[col=ct*32+cg*16+l15][k=ks*32+quad*8 .. +8]
// linear chunk = (((g*32+ct)*8+ks)*2+cg)*64 + quad*16 + l15, 16B each.
__global__ void vq_init_swz(const float* __restrict__ emb, u16* __restrict__ eh_sw,
                            u16* __restrict__ el_sw) {
  int tid = blockIdx.x * 256 + threadIdx.x;   // 0..65535
  int g = tid >> 15, rem = tid & 32767;
  int col = rem >> 5, kc = rem & 31;          // kc: 8-element k-chunk
  const float* src = emb + ((size_t)(g * MM + col)) * DD + kc * 8;
  float4 fa = *(const float4*)src;
  float4 fb = *(const float4*)(src + 4);
  float f[8] = {fa.x, fa.y, fa.z, fa.w, fb.x, fb.y, fb.z, fb.w};
  u16 hi[8], lo[8];
#pragma unroll
  for (int j = 0; j < 8; ++j) {
    hi[j] = f2bf(f[j]);
    lo[j] = f2bf(f[j] - bf2f(hi[j]));
  }
  int ct = col >> 5, cg = (col >> 4) & 1, l15 = col & 15;
  int ks = kc >> 2, quad = kc & 3;
  size_t chunk = ((((size_t)g * 32 + ct) * 8 + ks) * 2 + cg) * 64 + quad * 16 + l15;
  ushort4* dh = (ushort4*)(eh_sw + chunk * 8);
  ushort4* dl = (ushort4*)(el_sw + chunk * 8);
  dh[0] = make_ushort4(hi[0], hi[1], hi[2], hi[3]);
  dh[1] = make_ushort4(hi[4], hi[5], hi[6], hi[7]);
  dl[0] = make_ushort4(lo[0], lo[1], lo[2], lo[3]);
  dl[1] = make_ushort4(lo[4], lo[5], lo[6], lo[7]);
}

// ---- main v4: 128 rows/block, row-split waves (32 rows = 2 strips each),
// 32-col B tiles double-buffered (64KB LDS -> 2 blocks/CU), fast exp/log.
__global__ __launch_bounds__(256, 2) void vq_main4(
    const float* __restrict__ x, const float* __restrict__ emb,
    const float* __restrict__ gum, const float* __restrict__ sq_e,
    const u16* __restrict__ eh_sw, const u16* __restrict__ el_sw,
    float* __restrict__ out, u16* __restrict__ est, float* __restrict__ invZ_ws,
    int* __restrict__ hist, double* __restrict__ loss) {
  __shared__ u16 bt[2][16384];     // 2 x 32KB B tile buffers (hi | lo at +8192)
  __shared__ int fidx_lds[128];

  const int g = blockIdx.y;
  const int n0 = blockIdx.x * 128;
  const int t = threadIdx.x;
  const int wave = t >> 6, lane = t & 63;
  const int quad = lane >> 4, l15 = lane & 15;
  const int nw = n0 + wave * 32;   // this wave's first row

  // ---- build A fragments straight from global (2 strips x 8 ks, hi+lo) ----
  bf16x8 ah[2][8], al[2][8];
#pragma unroll
  for (int s = 0; s < 2; ++s) {
    const float* xr = x + (size_t)(nw + s * 16 + l15) * (GG * DD) + (size_t)g * DD + quad * 8;
#pragma unroll
    for (int ks = 0; ks < 8; ++ks) {
      float4 fa = *(const float4*)(xr + ks * 32);
      float4 fb = *(const float4*)(xr + ks * 32 + 4);
      float f[8] = {fa.x, fa.y, fa.z, fa.w, fb.x, fb.y, fb.z, fb.w};
#pragma unroll
      for (int j = 0; j < 8; ++j) {
        u16 h = f2bf(f[j]);
        ah[s][ks][j] = (short)h;
        al[s][ks][j] = (short)f2bf(f[j] - bf2f(h));
      }
    }
  }

  // hoisted per-(s,r) gum row bases and est bases
  const float* gumb[8];
  u16* estb[2];
#pragma unroll
  for (int s = 0; s < 2; ++s) {
    estb[s] = est + ((size_t)g * MM << 14) + nw + s * 16 + quad * 4;
#pragma unroll
    for (int r = 0; r < 4; ++r)
      gumb[s * 4 + r] =
          gum + ((size_t)(nw + s * 16 + quad * 4 + r) * GG + g) * MM;
  }
  const float* sqb = sq_e + g * MM + l15;

  const u16* sgh = eh_sw + (size_t)g * 32 * 8192;  // 32 tiles x 16KB (8192 u16)
  const u16* sgl = el_sw + (size_t)g * 32 * 8192;

  auto stage = [&](int ct, int buf) {
    const u16* sh = sgh + (size_t)ct * 8192;
    const u16* sl = sgl + (size_t)ct * 8192;
    u16* dh = &bt[buf][0];
    u16* dl = &bt[buf][8192];
#pragma unroll
    for (int j = 0; j < 4; ++j) {
      int slot = j * 4 + wave;   // 16 slots x 1KB per table
      async16(sh + slot * 512 + lane * 8, dh + slot * 512);
      async16(sl + slot * 512 + lane * 8, dl + slot * 512);
    }
  };

  // per-lane per-row state (8 rows: s in {0,1}, r in 0..3)
  float Zl[8], hv[8], z1[8], z2[8];
  int hid[8], i1[8], i2[8];
#pragma unroll
  for (int i = 0; i < 8; ++i) {
    Zl[i] = 0.f; hv[i] = -INFINITY; z1[i] = -INFINITY; z2[i] = -INFINITY;
    hid[i] = 0; i1[i] = 0; i2[i] = 0;
  }

  stage(0, 0);

#pragma unroll 1
  for (int ct = 0; ct < 32; ++ct) {
    __syncthreads();                     // stage(ct) landed; prev tile reads done
    if (ct < 31) stage(ct + 1, (ct + 1) & 1);
    const u16* bh_p = &bt[ct & 1][0];
    const u16* bl_p = &bt[ct & 1][8192];
#pragma unroll 1
    for (int cg = 0; cg < 2; ++cg) {
      const int colG = ct * 32 + cg * 16 + l15;
      float sqv = sqb[ct * 32 + cg * 16];
      float gv[8];
#pragma unroll
      for (int i = 0; i < 8; ++i) gv[i] = gumb[i][colG];

      f32x4 c00 = {0,0,0,0}, c01 = {0,0,0,0}, c02 = {0,0,0,0};
      f32x4 c10 = {0,0,0,0}, c11 = {0,0,0,0}, c12 = {0,0,0,0};
#pragma unroll
      for (int ks = 0; ks < 8; ++ks) {
        int off = ((ks * 2 + cg) * 64 + lane) * 8;
        bf16x8 bh = *(const bf16x8*)(bh_p + off);
        bf16x8 bl = *(const bf16x8*)(bl_p + off);
        c00 = __builtin_amdgcn_mfma_f32_16x16x32_bf16(ah[0][ks], bh, c00, 0, 0, 0);
        c01 = __builtin_amdgcn_mfma_f32_16x16x32_bf16(ah[0][ks], bl, c01, 0, 0, 0);
        c02 = __builtin_amdgcn_mfma_f32_16x16x32_bf16(al[0][ks], bh, c02, 0, 0, 0);
        c10 = __builtin_amdgcn_mfma_f32_16x16x32_bf16(ah[1][ks], bh, c10, 0, 0, 0);
        c11 = __builtin_amdgcn_mfma_f32_16x16x32_bf16(ah[1][ks], bl, c11, 0, 0, 0);
        c12 = __builtin_amdgcn_mfma_f32_16x16x32_bf16(al[1][ks], bh, c12, 0, 0, 0);
      }
#pragma unroll
      for (int s = 0; s < 2; ++s) {
        const f32x4& a0 = s ? c10 : c00;
        const f32x4& a1 = s ? c11 : c01;
        const f32x4& a2 = s ? c12 : c02;
        ushort4 pk;
        u16* pp = (u16*)&pk;
#pragma unroll
        for (int r = 0; r < 4; ++r) {
          float lp = 2.f * (a0[r] + a1[r] + a2[r]) - sqv + SHIFT;
          float ev = __expf(fminf(lp, 80.f));
          Zl[s * 4 + r] += ev;
          pp[r] = f2bf(ev);
          if (lp > hv[s * 4 + r]) { hv[s * 4 + r] = lp; hid[s * 4 + r] = colG; }
          float zz = lp - __logf(-__logf(gv[s * 4 + r]));
          if (zz > z1[s * 4 + r]) {
            z2[s * 4 + r] = z1[s * 4 + r]; i2[s * 4 + r] = i1[s * 4 + r];
            z1[s * 4 + r] = zz; i1[s * 4 + r] = colG;
          } else if (zz > z2[s * 4 + r]) {
            z2[s * 4 + r] = zz; i2[s * 4 + r] = colG;
          }
        }
        // est[g][m][n] bf16, 4 consecutive n per lane
        *(ushort4*)(estb[s] + ((size_t)colG << 14)) = pk;
      }
    }
  }

  // ---- per-row finalize: reduce over the 16 l15 lanes of each quad ----
#pragma unroll 1
  for (int s = 0; s < 2; ++s) {
#pragma unroll 1
    for (int r = 0; r < 4; ++r) {
      const int idx = s * 4 + r;
      const int row = wave * 32 + s * 16 + quad * 4 + r;
      const int n = n0 + row;
      float Zr = Zl[idx], hvr = hv[idx];
      int hir = hid[idx];
      float v1 = z1[idx], v2 = z2[idx];
      int j1 = i1[idx], j2 = i2[idx];
#pragma unroll
      for (int o = 1; o <= 8; o <<= 1) {
        Zr += __shfl_xor(Zr, o);
        float ohv = __shfl_xor(hvr, o); int ohi = __shfl_xor(hir, o);
        if (ohv > hvr || (ohv == hvr && ohi < hir)) { hvr = ohv; hir = ohi; }
        float w1 = __shfl_xor(v1, o), w2 = __shfl_xor(v2, o);
        int k1 = __shfl_xor(j1, o), k2 = __shfl_xor(j2, o);
        if (w1 > v1 || (w1 == v1 && k1 < j1)) {
          if (v1 > w2 || (v1 == w2 && j1 < k2)) { v2 = v1; j2 = j1; }
          else { v2 = w2; j2 = k2; }
          v1 = w1; j1 = k1;
        } else if (w1 > v2 || (w1 == v2 && k1 < j2)) { v2 = w1; j2 = k1; }
      }
      int fidx = j1;
      if (v1 - v2 < REFINE_GAP) {
        // exact fp64 re-check, 16-lane parallel over d
        const float* xrow = x + (size_t)n * (GG * DD) + (size_t)g * DD;
        const float* eA = emb + ((size_t)g * MM + j1) * DD;
        const float* eB = emb + ((size_t)g * MM + j2) * DD;
        double dA = 0, sA = 0, dB = 0, sB = 0;
#pragma unroll
        for (int k = 0; k < 16; ++k) {
          int d = l15 * 16 + k;
          double xv = (double)xrow[d];
          double ea = (double)eA[d], eb = (double)eB[d];
          dA += xv * ea; sA += ea * ea;
          dB += xv * eb; sB += eb * eb;
        }
#pragma unroll
        for (int o = 1; o <= 8; o <<= 1) {
          dA += __shfl_xor(dA, o); sA += __shfl_xor(sA, o);
          dB += __shfl_xor(dB, o); sB += __shfl_xor(sB, o);
        }
        double uA = (double)gum[((size_t)n * GG + g) * MM + j1];
        double uB = (double)gum[((size_t)n * GG + g) * MM + j2];
        double zA = 2.0 * dA - sA - log(-log(uA));
        double zB = 2.0 * dB - sB - log(-log(uB));
        if (zB > zA || (zB == zA && j2 < j1)) fidx = j2;
      }
      if (l15 == 0) {
        out[OFF_I + (size_t)n * GG + g] = (float)fidx;
        atomicAdd(&hist[g * MM + hir], 1);
        invZ_ws[g * NTOT + n] = 1.f / Zr;
        fidx_lds[row] = fidx;
      }
    }
  }
  __syncthreads();

  // ---- quantized rows + commitment-loss partial (coalesced) ----
  {
    float ls = 0.f;
#pragma unroll 4
    for (int j = 0; j < 32; ++j) {
      int idx = j * 256 + t;
      int row = idx >> 6, f4 = idx & 63;
      int n = n0 + row, fi = fidx_lds[row];
      float4 e4 = *(const float4*)&emb[((size_t)g * MM + fi) * DD + f4 * 4];
      float4 x4 = *(const float4*)&x[(size_t)n * (GG * DD) + (size_t)g * DD + f4 * 4];
      *(float4*)&out[OFF_Q + (size_t)n * (GG * DD) + (size_t)g * DD + f4 * 4] = e4;
      float dx = x4.x - e4.x, dy = x4.y - e4.y, dz = x4.z - e4.z, dw = x4.w - e4.w;
      ls += dx * dx + dy * dy + dz * dz + dw * dw;
    }
    ls = wave_sum_f(ls);
    if (lane == 0) atomicAdd(loss, (double)ls);
  }
}

// ---- avg_probs column reduction: avg[g][m] = sum_n est[g][m][n] * invZ[g][n]
__global__ void vq_avg(const u16* __restrict__ est, const float* __restrict__ invZ,
                       float* __restrict__ avg) {
  int wid = blockIdx.x * 4 + (threadIdx.x >> 6);   // 0..2047 = g*1024+m
  int lane = threadIdx.x & 63;
  const u16* base = est + ((size_t)wid << 14);
  const float* zp = invZ + ((wid >> 10) << 14);
  float acc = 0.f;
#pragma unroll 4
  for (int it = 0; it < 32; ++it) {
    int n = it * 512 + lane * 8;
    ushort4 ea = *(const ushort4*)(base + n);
    ushort4 eb = *(const ushort4*)(base + n + 4);
    float4 za = *(const float4*)(zp + n);
    float4 zb = *(const float4*)(zp + n + 4);
    acc += bf2f(ea.x) * za.x + bf2f(ea.y) * za.y +
           bf2f(ea.z) * za.z + bf2f(ea.w) * za.w;
    acc += bf2f(eb.x) * zb.x + bf2f(eb.y) * zb.y +
           bf2f(eb.z) * zb.z + bf2f(eb.w) * zb.w;
  }
  acc = wave_sum_f(acc);
  if (lane == 0) avg[wid] = acc;
}

// ---- finalize: entropies + loss ----
__global__ void vq_fin(const float* __restrict__ avg, const int* __restrict__ hist,
                       const double* __restrict__ loss, float* __restrict__ out) {
  int g = blockIdx.x, t = threadIdx.x;
  float cp = 0.f, pp = 0.f;
  for (int m = t; m < MM; m += 256) {
    float hp = (float)hist[g * MM + m] * (1.f / 16384.f);
    cp += hp * log2f(hp + 1e-10f);
    float ap = avg[g * MM + m] * (1.f / 16384.f);
    pp += ap * log2f(ap + 1e-10f);
  }
  cp = wave_sum_f(cp);
  pp = wave_sum_f(pp);
  __shared__ float sc[4], sp[4];
  int wave = t >> 6, lane = t & 63;
  if (lane == 0) { sc[wave] = cp; sp[wave] = pp; }
  __syncthreads();
  if (t == 0) {
    out[OFF_CP + g] = -(sc[0] + sc[1] + sc[2] + sc[3]);
    out[OFF_PP + g] = -(sp[0] + sp[1] + sp[2] + sp[3]);
    if (g == 0) out[OFF_L] = (float)(*loss * (1.0 / 8388608.0));
  }
}

extern "C" void kernel_launch(void* const* d_in, const int* in_sizes, int n_in,
                              void* d_out, int out_size, void* d_ws, size_t ws_size,
                              hipStream_t stream) {
  const float* x = (const float*)d_in[0];
  const float* emb = (const float*)d_in[1];
  const float* gum = (const float*)d_in[2];
  float* out = (float*)d_out;

  float* sq_e = (float*)d_ws;
  float* avg = (float*)((char*)d_ws + 8192);
  int* hist = (int*)((char*)d_ws + 16384);
  double* loss = (double*)((char*)d_ws + 24576);
  float* invZ = (float*)((char*)d_ws + WS_INVZ);
  u16* eh_sw = (u16*)((char*)d_ws + WS_EHSW);
  u16* el_sw = (u16*)((char*)d_ws + WS_ELSW);
  u16* est = (u16*)((char*)d_ws + WS_EST);

  vq_init2<<<512, 256, 0, stream>>>(emb, sq_e, avg, hist, loss);
  vq_init_swz<<<256, 256, 0, stream>>>(emb, eh_sw, el_sw);
  vq_main4<<<dim3(NTOT / 128, GG), 256, 0, stream>>>(
      x, emb, gum, sq_e, eh_sw, el_sw, out, est, invZ, hist, loss);
  vq_avg<<<512, 256, 0, stream>>>(est, invZ, avg);
  vq_fin<<<GG, 256, 0, stream>>>(avg, hist, loss, out);
}